// Round 1
// baseline (409.483 us; speedup 1.0000x reference)
//
#include <hip/hip_runtime.h>

// GNB dispersion — Round 8: direct-atomic rewrite.
// The bucket/scatter pipeline (R7, 202us) was latency/LDS-atomic-bound at 21% HBM /
// 8% VALU on every major dispatch. Replace with:
//   init (zero cn+outrep, build isCN bitmask) -> degree (isCN-filtered global int
//   atomics) -> params -> energy (stream edges, eval, native fp32 global atomic
//   into 16 bank-offset output replicas) -> reduce (sum replicas).
// Output replicas cut same-address atomic serialization ~16x (avg degree ~64).
// ws (words): [cn n][outrep REP*n][P2 2n (8B-aligned)][isCN nw]

#define REP 16
#define EB  256

__device__ __constant__ float2 GNB_RC6[87] = {
    {0.f, 0.f},
    {3.6516f, 95.99f},   {2.1843f, 40.67f},   {1.2711f, 70.21f},
    {3.3497f, 114.51f},  {2.7079f, 152.36f},  {1.8219f, 184.28f},
    {2.4667f, 482.54f},  {2.365f, 405.57f},   {1.5062f, 218.45f},
    {1.8233f, 174.81f},  {1.3974f, 181.7f},   {3.3515f, 263.02f},
    {3.0102f, 228.1f},   {3.1629f, 359.43f},  {3.2554f, 3222.12f},
    {2.9539f, 2144.49f}, {3.0368f, 2072.46f}, {2.6598f, 1357.42f},
    {4.0877f, 1406.65f}, {4.1275f, 1058.36f}, {9.7282f, 11498.73f},
    {8.5322f, 3361.33f}, {7.2344f, 2095.91f}, {5.3605f, 1049.31f},
    {3.718f, 966.27f},   {3.6408f, 1571.36f}, {3.4961f, 1183.59f},
    {3.5108f, 787.76f},  {3.0537f, 563.93f},  {3.0261f, 592.91f},
    {3.1735f, 430.82f},  {3.1773f, 812.57f},  {3.8357f, 4533.53f},
    {3.1109f, 3440.92f}, {3.2122f, 3859.82f}, {2.8263f, 2729.6f},
    {2.412f, 1864.19f},  {1.894f, 1175.73f},  {11.2061f, 32141.18f},
    {6.821f, 27655.14f}, {7.2367f, 2864.2f},  {3.901f, 3563.45f},
    {4.0857f, 3266.43f}, {4.045f, 3967.23f},  {3.4813f, 2233.82f},
    {3.0487f, 1393.49f}, {2.7795f, 1315.09f}, {2.8673f, 1311.47f},
    {3.3339f, 1460.56f}, {3.0086f, 1662.99f}, {3.9919f, 8089.97f},
    {3.4209f, 6887.05f}, {3.5649f, 8799.32f}, {3.0288f, 6136.5f},
    {2.262f, 3757.31f},  {1.3837f, 2561.18f}, {12.171f, 66580.83f},
    {0.f,0.f},{0.f,0.f},{0.f,0.f},{0.f,0.f},{0.f,0.f},{0.f,0.f},{0.f,0.f},
    {0.f,0.f},{0.f,0.f},{0.f,0.f},{0.f,0.f},{0.f,0.f},{0.f,0.f},{0.f,0.f},
    {6.0791f, 27593.76f}, {5.7661f, 15364.65f}, {3.6366f, 2734.5f},
    {4.241f, 4801.82f},   {4.1348f, 5685.94f},  {3.4213f, 2786.0f},
    {3.2486f, 2699.79f},  {2.9588f, 2282.6f},   {2.9381f, 2476.79f},
    {2.7711f, 2988.7f},   {2.5816f, 2506.63f},  {3.785f, 8916.84f},
    {3.5381f, 8694.22f},  {3.6985f, 11821.61f}, {3.0551f, 8410.64f},
};

__device__ __forceinline__ void atomic_fadd(float* p, float v) {
#if defined(__HIP_PLATFORM_AMD__)
    unsafeAtomicAdd(p, v);   // native global_atomic_add_f32, no CAS loop
#else
    atomicAdd(p, v);
#endif
}

// Zero cn + outrep (contiguous at ws start), build bit-packed isCN mask.
__global__ void gnb_init(const int* __restrict__ Z, unsigned* __restrict__ isCN,
                         int nw, int n_nodes, int4* __restrict__ zp4, int zq,
                         int* __restrict__ zp, long zwords) {
    int stride = gridDim.x * blockDim.x;
    int t0 = blockIdx.x * blockDim.x + threadIdx.x;
    int4 z4 = make_int4(0, 0, 0, 0);
    for (int i = t0; i < zq; i += stride) zp4[i] = z4;
    for (long i = (long)zq * 4 + t0; i < zwords; i += stride) zp[i] = 0;
    for (int w = t0; w < nw; w += stride) {
        unsigned m = 0;
        int base = w << 5;
        int lim = n_nodes - base; if (lim > 32) lim = 32;
        for (int k = 0; k < lim; ++k) {
            int z = Z[base + k];
            if (z == 6 || z == 7) m |= (1u << k);
        }
        isCN[w] = m;
    }
}

// Filtered degree: only C/N nodes (2.3% of edges) generate atomics.
__global__ void __launch_bounds__(EB)
gnb_degree(const int* __restrict__ recv, const unsigned* __restrict__ isCN,
           int* __restrict__ cn, int n_edges) {
    int base = (blockIdx.x * EB + threadIdx.x) * 4;
    if (base + 3 < n_edges) {
        int4 rv = *(const int4*)(recv + base);
        int rr[4] = {rv.x, rv.y, rv.z, rv.w};
        #pragma unroll
        for (int j = 0; j < 4; ++j) {
            unsigned r = (unsigned)rr[j];
            if ((isCN[r >> 5] >> (r & 31)) & 1u) atomicAdd(&cn[r], 1);
        }
    } else {
        for (int j = 0; j < 4; ++j) {
            int e = base + j;
            if (e < n_edges) {
                unsigned r = (unsigned)recv[e];
                if ((isCN[r >> 5] >> (r & 31)) & 1u) atomicAdd(&cn[r], 1);
            }
        }
    }
}

__global__ void gnb_params(const int* __restrict__ Z, const int* __restrict__ cn,
                           float2* __restrict__ P2, int n_nodes) {
    int i = blockIdx.x * blockDim.x + threadIdx.x;
    if (i >= n_nodes) return;
    int z = Z[i];
    float Rp, C6;
    if (z == 6) {
        if (cn[i] <= 3) { Rp = 2.2348f; C6 = 429.69f; }
        else            { Rp = 1.8219f; C6 = 184.28f; }
    } else if (z == 7) {
        if (cn[i] <= 2) { Rp = 2.6454f; C6 = 720.18f; }
        else            { Rp = 2.4667f; C6 = 482.54f; }
    } else {
        float2 rc = GNB_RC6[z];
        Rp = rc.x; C6 = rc.y;
    }
    P2[i] = make_float2(sqrtf(C6), sqrtf(sqrtf(Rp)));
}

__device__ __forceinline__ float gnb_energy_eval(float2 ps, float2 pr, float rlen) {
    float env;
    if (rlen < 8.0f) {
        env = 1.0f;
    } else {
        float x = (rlen - 8.0f) * 0.5f;          // callers guarantee rlen < 10 -> x < 1
        float x2 = x * x;
        float x6 = x2 * x2 * x2;
        env = 1.0f - 28.0f * x6 + 48.0f * x6 * x - 21.0f * x6 * x2;
    }
    float sR  = ps.y * pr.y;                     // sqrt(R_ij)
    float C6  = ps.x * pr.x;                     // sqrt(C6_s*C6_r)
    float Rij = sR * sR;
    float R3  = Rij * Rij * Rij;
    float R6  = R3 * R3;
    float r0  = 0.4f * sR + 4.0f;
    float t   = r0 / rlen;
    float t2 = t * t, t4 = t2 * t2, t8 = t4 * t4;
    float t14 = t8 * t4 * t2;
    float fd = 1.0f / (1.0f + 6.0f * t14);
    float rl2 = rlen * rlen;
    float r6 = rl2 * rl2 * rl2;
    return -0.5f * C6 / (R6 + r6) * fd * env;
}

// Streaming edge kernel: int4/float4 loads, two L2-resident P2 gathers, one native
// fp32 global atomic per kept edge into a wave-cycled replica of the output.
__global__ void __launch_bounds__(EB)
gnb_energy(const int* __restrict__ send, const int* __restrict__ recv,
           const float* __restrict__ len, const float2* __restrict__ P2,
           float* __restrict__ outrep, int n_edges, int n_nodes) {
    float* myout = outrep +
        (size_t)(((blockIdx.x << 2) + (threadIdx.x >> 6)) & (REP - 1)) * n_nodes;
    int base = (blockIdx.x * EB + threadIdx.x) * 4;
    if (base + 3 < n_edges) {
        int4   sv = *(const int4*)(send + base);
        int4   rv = *(const int4*)(recv + base);
        float4 lv = *(const float4*)(len + base);
        int ss[4] = {sv.x, sv.y, sv.z, sv.w};
        int rr[4] = {rv.x, rv.y, rv.z, rv.w};
        float ll[4] = {lv.x, lv.y, lv.z, lv.w};
        #pragma unroll
        for (int j = 0; j < 4; ++j) {
            if (ll[j] < 10.0f) {
                float2 ps = P2[ss[j]];
                float2 pr = P2[rr[j]];
                float e = gnb_energy_eval(ps, pr, ll[j]);
                atomic_fadd(&myout[rr[j]], e);
            }
        }
    } else {
        for (int j = 0; j < 4; ++j) {
            int e = base + j;
            if (e < n_edges) {
                float l = len[e];
                if (l < 10.0f) {
                    float en = gnb_energy_eval(P2[send[e]], P2[recv[e]], l);
                    atomic_fadd(&myout[recv[e]], en);
                }
            }
        }
    }
}

__global__ void gnb_reduce(const float* __restrict__ outrep, float* __restrict__ out,
                           int n_nodes) {
    int i = blockIdx.x * blockDim.x + threadIdx.x;
    if (i >= n_nodes) return;
    float s = 0.0f;
    #pragma unroll
    for (int rpl = 0; rpl < REP; ++rpl) s += outrep[(size_t)rpl * n_nodes + i];
    out[i] = s;
}

extern "C" void kernel_launch(void* const* d_in, const int* in_sizes, int n_in,
                              void* d_out, int out_size, void* d_ws, size_t ws_size,
                              hipStream_t stream) {
    const int*   Z    = (const int*)d_in[0];
    const int*   eidx = (const int*)d_in[1];
    const float* len  = (const float*)d_in[2];
    float*       out  = (float*)d_out;

    const int n_nodes = in_sizes[0];
    const int n_edges = in_sizes[2];
    const int* send = eidx;
    const int* recv = eidx + n_edges;

    const int nw = (n_nodes + 31) >> 5;

    // ws layout (words): [cn n][outrep REP*n][P2 2n (8B aligned)][isCN nw]
    char* ws = (char*)d_ws;
    int*      cn     = (int*)ws;
    float*    outrep = (float*)(ws + (size_t)n_nodes * 4);
    size_t    p2off  = (((size_t)(1 + REP) * n_nodes) + 1) & ~(size_t)1; // even word
    float2*   P2     = (float2*)(ws + p2off * 4);
    unsigned* isCN   = (unsigned*)(ws + (p2off + (size_t)2 * n_nodes) * 4);

    long zwords = (long)(1 + REP) * n_nodes;     // cn + outrep, contiguous
    int  zq     = (int)(zwords / 4);

    const int B = 256;
    int node_blocks = (n_nodes + B - 1) / B;
    int edge_blocks = (n_edges + EB * 4 - 1) / (EB * 4);

    gnb_init<<<256, B, 0, stream>>>(Z, isCN, nw, n_nodes, (int4*)ws, zq,
                                    (int*)ws, zwords);
    gnb_degree<<<edge_blocks, EB, 0, stream>>>(recv, isCN, cn, n_edges);
    gnb_params<<<node_blocks, B, 0, stream>>>(Z, cn, P2, n_nodes);
    gnb_energy<<<edge_blocks, EB, 0, stream>>>(send, recv, len, P2, outrep,
                                               n_edges, n_nodes);
    gnb_reduce<<<node_blocks, B, 0, stream>>>(outrep, out, n_nodes);
}

// Round 3
// 228.562 us; speedup vs baseline: 1.7916x; 1.7916x over previous
//
#include <hip/hip_runtime.h>

// GNB dispersion — Round 10: resubmit of R9 (container infra failure, no counters).
// R8 proved device-scope fp32 atomics cap at ~20/ns (301us) -> back to LDS binning.
// vs R7: single edge read (tile in registers), per-wave LDS histograms whose
// atomic-return IS the placement offset (no pos[] second pass), parallel shfl scan
// (no serial 98-loop), and energy evaluated AT scatter time so the accumulate
// kernel is gather-free.
//   init (zero + isCN) -> degree -> params -> scatter(+eval) -> accum -> ovf -> reduce
// Record: uint2{ rlow, e_bits }. Bucket id implied by storage. NB2 <= 128.
// ws (words): [cursor 128][ocur 8][cn n][ovf n][P2 2n][isCN nwp]
//             [rep NB2*ES*1024][ovrec uint2 ocap][buckets uint2 NB2*cap]

#define B2SHIFT 10
#define B2SIZE  1024
#define TILE    4096
#define SBLK    512
#define NWAVE   8
#define ESLICES 32
#define MAXB    128
#define EB      256

__device__ __constant__ float2 GNB_RC6[87] = {
    {0.f, 0.f},
    {3.6516f, 95.99f},   {2.1843f, 40.67f},   {1.2711f, 70.21f},
    {3.3497f, 114.51f},  {2.7079f, 152.36f},  {1.8219f, 184.28f},
    {2.4667f, 482.54f},  {2.365f, 405.57f},   {1.5062f, 218.45f},
    {1.8233f, 174.81f},  {1.3974f, 181.7f},   {3.3515f, 263.02f},
    {3.0102f, 228.1f},   {3.1629f, 359.43f},  {3.2554f, 3222.12f},
    {2.9539f, 2144.49f}, {3.0368f, 2072.46f}, {2.6598f, 1357.42f},
    {4.0877f, 1406.65f}, {4.1275f, 1058.36f}, {9.7282f, 11498.73f},
    {8.5322f, 3361.33f}, {7.2344f, 2095.91f}, {5.3605f, 1049.31f},
    {3.718f, 966.27f},   {3.6408f, 1571.36f}, {3.4961f, 1183.59f},
    {3.5108f, 787.76f},  {3.0537f, 563.93f},  {3.0261f, 592.91f},
    {3.1735f, 430.82f},  {3.1773f, 812.57f},  {3.8357f, 4533.53f},
    {3.1109f, 3440.92f}, {3.2122f, 3859.82f}, {2.8263f, 2729.6f},
    {2.412f, 1864.19f},  {1.894f, 1175.73f},  {11.2061f, 32141.18f},
    {6.821f, 27655.14f}, {7.2367f, 2864.2f},  {3.901f, 3563.45f},
    {4.0857f, 3266.43f}, {4.045f, 3967.23f},  {3.4813f, 2233.82f},
    {3.0487f, 1393.49f}, {2.7795f, 1315.09f}, {2.8673f, 1311.47f},
    {3.3339f, 1460.56f}, {3.0086f, 1662.99f}, {3.9919f, 8089.97f},
    {3.4209f, 6887.05f}, {3.5649f, 8799.32f}, {3.0288f, 6136.5f},
    {2.262f, 3757.31f},  {1.3837f, 2561.18f}, {12.171f, 66580.83f},
    {0.f,0.f},{0.f,0.f},{0.f,0.f},{0.f,0.f},{0.f,0.f},{0.f,0.f},{0.f,0.f},
    {0.f,0.f},{0.f,0.f},{0.f,0.f},{0.f,0.f},{0.f,0.f},{0.f,0.f},{0.f,0.f},
    {6.0791f, 27593.76f}, {5.7661f, 15364.65f}, {3.6366f, 2734.5f},
    {4.241f, 4801.82f},   {4.1348f, 5685.94f},  {3.4213f, 2786.0f},
    {3.2486f, 2699.79f},  {2.9588f, 2282.6f},   {2.9381f, 2476.79f},
    {2.7711f, 2988.7f},   {2.5816f, 2506.63f},  {3.785f, 8916.84f},
    {3.5381f, 8694.22f},  {3.6985f, 11821.61f}, {3.0551f, 8410.64f},
};

__device__ __forceinline__ void atomic_fadd(float* p, float v) {
#if defined(__HIP_PLATFORM_AMD__)
    unsafeAtomicAdd(p, v);
#else
    atomicAdd(p, v);
#endif
}

// Zero [cursor|ocur|cn|ovf] (contiguous at ws start) + build isCN bitmask.
__global__ void gnb_init(const int* __restrict__ Z, unsigned* __restrict__ isCN,
                         int nw, int n_nodes, int4* __restrict__ zp4, int zq,
                         int* __restrict__ zp, int zwords) {
    int stride = gridDim.x * blockDim.x;
    int t0 = blockIdx.x * blockDim.x + threadIdx.x;
    int4 z4 = make_int4(0, 0, 0, 0);
    for (int i = t0; i < zq; i += stride) zp4[i] = z4;
    for (int i = zq * 4 + t0; i < zwords; i += stride) zp[i] = 0;
    for (int w = t0; w < nw; w += stride) {
        unsigned m = 0;
        int base = w << 5;
        int lim = n_nodes - base; if (lim > 32) lim = 32;
        for (int k = 0; k < lim; ++k) {
            int z = Z[base + k];
            if (z == 6 || z == 7) m |= (1u << k);
        }
        isCN[w] = m;
    }
}

// Degree over ALL edges; only C/N receivers (2.3% of edges) generate atomics.
__global__ void __launch_bounds__(EB)
gnb_degree(const int* __restrict__ recv, const unsigned* __restrict__ isCN,
           int* __restrict__ cn, int n_edges) {
    int base = (blockIdx.x * EB + threadIdx.x) * 4;
    if (base + 3 < n_edges) {
        int4 rv = *(const int4*)(recv + base);
        int rr[4] = {rv.x, rv.y, rv.z, rv.w};
        #pragma unroll
        for (int j = 0; j < 4; ++j) {
            unsigned r = (unsigned)rr[j];
            if ((isCN[r >> 5] >> (r & 31)) & 1u) atomicAdd(&cn[r], 1);
        }
    } else {
        for (int j = 0; j < 4; ++j) {
            int e = base + j;
            if (e < n_edges) {
                unsigned r = (unsigned)recv[e];
                if ((isCN[r >> 5] >> (r & 31)) & 1u) atomicAdd(&cn[r], 1);
            }
        }
    }
}

__global__ void gnb_params(const int* __restrict__ Z, const int* __restrict__ cn,
                           float2* __restrict__ P2, int n_nodes) {
    int i = blockIdx.x * blockDim.x + threadIdx.x;
    if (i >= n_nodes) return;
    int z = Z[i];
    float Rp, C6;
    if (z == 6) {
        if (cn[i] <= 3) { Rp = 2.2348f; C6 = 429.69f; }
        else            { Rp = 1.8219f; C6 = 184.28f; }
    } else if (z == 7) {
        if (cn[i] <= 2) { Rp = 2.6454f; C6 = 720.18f; }
        else            { Rp = 2.4667f; C6 = 482.54f; }
    } else {
        float2 rc = GNB_RC6[z];
        Rp = rc.x; C6 = rc.y;
    }
    P2[i] = make_float2(sqrtf(C6), sqrtf(sqrtf(Rp)));
}

__device__ __forceinline__ float gnb_energy_eval(float2 ps, float2 pr, float rlen) {
    float env;
    if (rlen < 8.0f) {
        env = 1.0f;
    } else {
        float x = (rlen - 8.0f) * 0.5f;          // callers guarantee rlen < 10 -> x < 1
        float x2 = x * x;
        float x6 = x2 * x2 * x2;
        env = 1.0f - 28.0f * x6 + 48.0f * x6 * x - 21.0f * x6 * x2;
    }
    float sR  = ps.y * pr.y;                     // sqrt(R_ij)
    float C6  = ps.x * pr.x;                     // sqrt(C6_s*C6_r)
    float Rij = sR * sR;
    float R3  = Rij * Rij * Rij;
    float R6  = R3 * R3;
    float r0  = 0.4f * sR + 4.0f;
    float t   = r0 / rlen;
    float t2 = t * t, t4 = t2 * t2, t8 = t4 * t4;
    float t14 = t8 * t4 * t2;
    float fd = 1.0f / (1.0f + 6.0f * t14);
    float rl2 = rlen * rlen;
    float r6 = rl2 * rl2 * rl2;
    return -0.5f * C6 / (R6 + r6) * fd * env;
}

// Fused scatter+eval, single edge read held in registers.
// pass A: per-wave LDS histogram; atomic-return = within-wave placement offset.
// scan:   128-thread column sums + one wave64 shfl scan (no serial loop).
// pass B: place (rlow, e) records bucket-sorted in LDS from registers.
// pass C: coalesced copy of bucket runs to global (overflow -> queue).
__global__ void __launch_bounds__(SBLK)
gnb_scatter(const int* __restrict__ send, const int* __restrict__ recv,
            const float* __restrict__ len, const float2* __restrict__ P2,
            uint2* __restrict__ buckets, unsigned* __restrict__ cursor,
            uint2* __restrict__ ovrec, unsigned* __restrict__ ocur,
            int n_edges, int cap, unsigned ocap, int NB2) {
    __shared__ unsigned hist[NWAVE][MAXB];
    __shared__ unsigned waveBase[NWAVE][MAXB];
    __shared__ unsigned cntS[MAXB];
    __shared__ unsigned startp[MAXB + 1];
    __shared__ unsigned gbase[MAXB];
    __shared__ uint2 srec[TILE];             // 32 KB, bucket-sorted records
    __shared__ unsigned char bmap[TILE];     // 4 KB, slot -> bucket
    const int tid = threadIdx.x;
    const int w   = tid >> 6;
    const int e0  = blockIdx.x * TILE;

    for (int i = tid; i < NWAVE * MAXB; i += SBLK) (&hist[0][0])[i] = 0;
    __syncthreads();

    // pass A: load tile into registers, eval energy, per-wave histogram.
    // pk packs: b(7) | rlow<<7 (10) | waveOff<<17 (10); 0xFFFFFFFF = not kept.
    unsigned pk[2][4];
    float    ev[2][4];
    const bool full = (e0 + TILE <= n_edges);
    #pragma unroll
    for (int k = 0; k < 2; ++k) {
        int base = e0 + (k * SBLK + tid) * 4;
        int ss[4]; int rr[4]; float ll[4];
        if (full) {
            int4   sv = *(const int4*)(send + base);
            int4   rv = *(const int4*)(recv + base);
            float4 lv = *(const float4*)(len + base);
            ss[0]=sv.x; ss[1]=sv.y; ss[2]=sv.z; ss[3]=sv.w;
            rr[0]=rv.x; rr[1]=rv.y; rr[2]=rv.z; rr[3]=rv.w;
            ll[0]=lv.x; ll[1]=lv.y; ll[2]=lv.z; ll[3]=lv.w;
        } else {
            for (int j = 0; j < 4; ++j) {
                int e = base + j;
                bool ok = (e < n_edges);
                ss[j] = ok ? send[e] : 0;
                rr[j] = ok ? recv[e] : 0;
                ll[j] = ok ? len[e]  : 1.0e9f;
            }
        }
        #pragma unroll
        for (int j = 0; j < 4; ++j) {
            if (ll[j] < 10.0f) {
                float2 ps = P2[ss[j]];
                float2 pr = P2[rr[j]];
                ev[k][j] = gnb_energy_eval(ps, pr, ll[j]);
                unsigned r = (unsigned)rr[j];
                unsigned b = r >> B2SHIFT;
                unsigned off = atomicAdd(&hist[w][b], 1u);
                pk[k][j] = b | ((r & (B2SIZE - 1)) << 7) | (off << 17);
            } else {
                pk[k][j] = 0xFFFFFFFFu;
            }
        }
    }
    __syncthreads();

    // scan: column sums over waves, then exclusive scan over 128 buckets (wave 0).
    if (tid < MAXB) {
        unsigned acc = 0;
        #pragma unroll
        for (int ww = 0; ww < NWAVE; ++ww) {
            waveBase[ww][tid] = acc;
            acc += hist[ww][tid];
        }
        cntS[tid] = acc;
    }
    __syncthreads();
    if (tid < 64) {
        unsigned a0 = cntS[2 * tid], a1 = cntS[2 * tid + 1];
        unsigned s = a0 + a1;
        unsigned sc = s;
        #pragma unroll
        for (int d = 1; d < 64; d <<= 1) {
            unsigned t = __shfl_up(sc, d);
            if (tid >= d) sc += t;
        }
        unsigned excl = sc - s;
        startp[2 * tid]     = excl;
        startp[2 * tid + 1] = excl + a0;
        if (tid == 63) startp[MAXB] = sc;
    }
    __syncthreads();
    if (tid < NB2) {
        unsigned c = cntS[tid];
        gbase[tid] = c ? atomicAdd(&cursor[tid], c) : 0u;
    }
    __syncthreads();

    // pass B: place records from registers, bucket-sorted.
    #pragma unroll
    for (int k = 0; k < 2; ++k) {
        #pragma unroll
        for (int j = 0; j < 4; ++j) {
            unsigned p = pk[k][j];
            if (p != 0xFFFFFFFFu) {
                unsigned b    = p & (MAXB - 1);
                unsigned rlow = (p >> 7) & (B2SIZE - 1);
                unsigned off  = p >> 17;
                unsigned slot = startp[b] + waveBase[w][b] + off;
                srec[slot] = make_uint2(rlow, __float_as_uint(ev[k][j]));
                bmap[slot] = (unsigned char)b;
            }
        }
    }
    __syncthreads();

    // pass C: coalesced copy — consecutive slots hit contiguous bucket runs.
    unsigned total = startp[MAXB];
    for (unsigned i = tid; i < total; i += SBLK) {
        unsigned b = bmap[i];
        unsigned g = gbase[b] + (i - startp[b]);
        uint2 rec = srec[i];
        if (g < (unsigned)cap) {
            buckets[(size_t)b * cap + g] = rec;
        } else {
            unsigned o = atomicAdd(ocur, 1u);
            if (o < ocap) ovrec[o] = make_uint2((b << B2SHIFT) | rec.x, rec.y);
        }
    }
}

// Gather-free accumulate: stream records, LDS fp32 add into 2 replicas.
__global__ void __launch_bounds__(256)
gnb_accum(const uint2* __restrict__ buckets, const unsigned* __restrict__ cursor,
          float* __restrict__ rep, int cap) {
    __shared__ float acc[2][B2SIZE + 8];
    const int b   = blockIdx.x / ESLICES;
    const int sl  = blockIdx.x % ESLICES;
    const int tid = threadIdx.x;
    const int rr  = (tid >> 6) & 1;

    for (int i = tid; i < 2 * (B2SIZE + 8); i += 256) acc[0][i] = 0.0f;
    __syncthreads();

    unsigned count = cursor[b];
    if (count > (unsigned)cap) count = (unsigned)cap;
    unsigned seg = (count + ESLICES - 1) / ESLICES;
    unsigned st  = (unsigned)sl * seg;
    unsigned en  = st + seg; if (en > count) en = count;

    const uint2* src = buckets + (size_t)b * cap;
    for (unsigned i = st + tid; i < en; i += 256) {
        uint2 rec = src[i];
        atomicAdd(&acc[rr][rec.x], __uint_as_float(rec.y));
    }
    __syncthreads();

    float* dst = rep + (size_t)blockIdx.x * B2SIZE;
    for (int i = tid; i < B2SIZE; i += 256) dst[i] = acc[0][i] + acc[1][i];
}

__global__ void gnb_ovf_energy(const uint2* __restrict__ ovrec,
                               const unsigned* __restrict__ ocur,
                               float* __restrict__ ovf, unsigned ocap) {
    unsigned n = *ocur; if (n > ocap) n = ocap;
    int stride = gridDim.x * blockDim.x;
    for (unsigned i = blockIdx.x * blockDim.x + threadIdx.x; i < n; i += stride) {
        uint2 rec = ovrec[i];
        atomic_fadd(&ovf[rec.x], __uint_as_float(rec.y));
    }
}

__global__ void gnb_reduce(const float* __restrict__ rep, const float* __restrict__ ovf,
                           float* __restrict__ out, int n_nodes) {
    int i = blockIdx.x * blockDim.x + threadIdx.x;
    if (i >= n_nodes) return;
    int b = i >> B2SHIFT;
    int j = i & (B2SIZE - 1);
    const float* src = rep + ((size_t)b * ESLICES) * B2SIZE + j;
    float sum = ovf[i];
    #pragma unroll
    for (int s = 0; s < ESLICES; ++s) sum += src[(size_t)s * B2SIZE];
    out[i] = sum;
}

extern "C" void kernel_launch(void* const* d_in, const int* in_sizes, int n_in,
                              void* d_out, int out_size, void* d_ws, size_t ws_size,
                              hipStream_t stream) {
    const int*   Z    = (const int*)d_in[0];
    const int*   eidx = (const int*)d_in[1];
    const float* len  = (const float*)d_in[2];
    float*       out  = (float*)d_out;

    const int n_nodes = in_sizes[0];
    const int n_edges = in_sizes[2];
    const int* send = eidx;
    const int* recv = eidx + n_edges;

    const int NB2 = (n_nodes + B2SIZE - 1) >> B2SHIFT;   // 98 for n=100000
    const int nw  = (n_nodes + 31) >> 5;
    const int nwp = (nw + 7) & ~7;

    // ws layout (words): [cursor 128][ocur 8][cn n][ovf n][P2 2n][isCN nwp][rep][tail]
    char* ws = (char*)d_ws;
    unsigned* cursor = (unsigned*)ws;                                          // 128
    unsigned* ocur   = (unsigned*)(ws + MAXB * 4);                             // 8
    int*      cn     = (int*)(ws + (MAXB + 8) * 4);                            // n
    float*    ovf    = (float*)(ws + ((size_t)n_nodes + MAXB + 8) * 4);        // n
    float2*   P2     = (float2*)(ws + ((size_t)2 * n_nodes + MAXB + 8) * 4);   // 2n
    unsigned* isCN   = (unsigned*)(ws + ((size_t)4 * n_nodes + MAXB + 8) * 4); // nwp
    float*    rep    = (float*)((char*)isCN + (size_t)nwp * 4);
    size_t rep_w     = (size_t)NB2 * ESLICES * B2SIZE;
    char*     tail   = (char*)rep + rep_w * 4;

    size_t fixed_words = (size_t)4 * n_nodes + MAXB + 8 + nwp + rep_w;
    size_t total_words = ws_size / 4;
    size_t avail = total_words > fixed_words ? total_words - fixed_words : 0;
    size_t ovw = avail / 32;                      // ~3% to overflow queue
    unsigned ocap = (unsigned)(ovw / 2);          // uint2 records
    long cap = (long)((avail - ovw) / (2 * (size_t)NB2));
    if (cap > n_edges) cap = n_edges;
    if (cap < 0) cap = 0;
    uint2* ovrec   = (uint2*)tail;
    uint2* buckets = (uint2*)(tail + (size_t)ocap * 8);

    const int B = 256;
    int node_blocks = (n_nodes + B - 1) / B;
    int edge4_blocks = (n_edges + EB * 4 - 1) / (EB * 4);
    int scat_blocks = (n_edges + TILE - 1) / TILE;
    int zero_words  = 2 * n_nodes + MAXB + 8;     // cursor + ocur + cn + ovf
    int zq = zero_words / 4;

    gnb_init<<<256, B, 0, stream>>>(Z, isCN, nw, n_nodes, (int4*)ws, zq,
                                    (int*)ws, zero_words);
    gnb_degree<<<edge4_blocks, EB, 0, stream>>>(recv, isCN, cn, n_edges);
    gnb_params<<<node_blocks, B, 0, stream>>>(Z, cn, P2, n_nodes);
    gnb_scatter<<<scat_blocks, SBLK, 0, stream>>>(send, recv, len, P2, buckets,
                                                  cursor, ovrec, ocur, n_edges,
                                                  (int)cap, ocap, NB2);
    gnb_accum<<<NB2 * ESLICES, B, 0, stream>>>(buckets, cursor, rep, (int)cap);
    gnb_ovf_energy<<<8, B, 0, stream>>>(ovrec, ocur, ovf, ocap);
    gnb_reduce<<<node_blocks, B, 0, stream>>>(rep, ovf, out, n_nodes);
}